// Round 11
// baseline (283.361 us; speedup 1.0000x reference)
//
#include <hip/hip_runtime.h>

// SparseMCFModel: the GNN is dead code. fw_e = 1/(outdeg(src_e)+1e-9) exactly
// (softmax over per-segment-constant scores). Flow loop collapses to node
// space: r_0 = invdeg; r_{k+1}[n] = relu(sum_{e:dst=n} r_k[src_e] - d0[n]) *
// invdeg[n]; flow[e] = r_10[src[e]]; fw[e] = invdeg[src[e]]; cost = sum flow^2.
//
// R1->R2: no single-address cost atomic; CSR gather spmv.       1268 -> 428 us
// R2->R3: bucket partition (atomic-free except outdeg hist).     428 -> 284 us
// R3->R4: zero global atomics, CHUNK 4096.                       284 -> 219 us
// R4->R5: full counting sort -> CSR-by-dst, atomic-free spmv.    219 -> 220 us
// R5->R6: smaller counts matrix, fused scatter, fused bucket.    220 -> 188 us
// R6->R7: cooperative grid.sync — ~100us/sync (XCD non-coherence). -> 1188 us
// R7->R8: threadfence-ticket = same-address atomic serialization.  -> 230 us
// R8->R9: ticket dropped; last spmv iter emits float2{r10,invdeg}.  -> 172 us
// R9->R10: CHUNK 8192, no scan_partials kernel, dz float2.          -> 170 us
// R10->R11: spmv lanes issued 4 scalar csr loads each (4 transactions/16B).
//   CSR rows padded to x4 + 16B-aligned bucket bases -> each lane reads ONE
//   int4 (64MB csr stream over 10 iters at 1/4 the load count). Pad slots
//   point to dummy node N with r[N]=0 (exact sums); inter-bucket gaps
//   dummy-filled. csr grows ~5% (E + ~302K entries).

static constexpr int BLK      = 256;    // spmv / final / reduce
static constexpr int BLK_B    = 512;    // hist / scatter / bucket
static constexpr int SCAN_BLK = 1024;
static constexpr int CHUNK    = 8192;   // edges per partition block
static constexpr int LB       = 9;      // log2(nodes per bucket)
static constexpr int BN       = 512;    // nodes per bucket
static constexpr int MAXNBS   = 256;    // max scan blocks (nbs = 76 here)
static constexpr int BSLACK   = 1540;   // per-bucket csr slack (>= 3*512 + align 4)

// ---------- build passes ----------

__global__ void hist_kernel(const int* __restrict__ src, const int* __restrict__ dst,
                            int* __restrict__ counts, int E, int B, int nb, int M) {
    extern __shared__ int lh[];              // 8 replicas x [0,B) dst | [B,2B) src
    const int nbins = 2 * B;
    for (int i = threadIdx.x; i < 8 * nbins; i += blockDim.x) lh[i] = 0;
    __syncthreads();
    int* my = lh + (threadIdx.x >> 6) * nbins;
    int base = blockIdx.x * CHUNK;
    int end  = base + CHUNK < E ? base + CHUNK : E;
    int i4beg = base >> 2, i4end = end >> 2;
    for (int i = i4beg + threadIdx.x; i < i4end; i += blockDim.x) {
        int4 s4 = ((const int4*)src)[i];
        int4 d4 = ((const int4*)dst)[i];
        atomicAdd(&my[d4.x >> LB], 1); atomicAdd(&my[B + (s4.x >> LB)], 1);
        atomicAdd(&my[d4.y >> LB], 1); atomicAdd(&my[B + (s4.y >> LB)], 1);
        atomicAdd(&my[d4.z >> LB], 1); atomicAdd(&my[B + (s4.z >> LB)], 1);
        atomicAdd(&my[d4.w >> LB], 1); atomicAdd(&my[B + (s4.w >> LB)], 1);
    }
    if (blockIdx.x == (int)gridDim.x - 1 && threadIdx.x == 0) {   // scalar tail
        for (int e = i4end << 2; e < end; ++e) {
            atomicAdd(&my[dst[e] >> LB], 1);
            atomicAdd(&my[B + (src[e] >> LB)], 1);
        }
    }
    __syncthreads();
    for (int i = threadIdx.x; i < nbins; i += blockDim.x) {
        int s = 0;
        #pragma unroll
        for (int r = 0; r < 8; ++r) s += lh[r * nbins + i];
        if (i < B) counts[i * nb + blockIdx.x] = s;               // bin-major
        else       counts[M + (i - B) * nb + blockIdx.x] = s;
    }
}

__global__ void scan_block_kernel(int* __restrict__ data, int* __restrict__ blocksum, int M2) {
    __shared__ int lds[SCAN_BLK];
    int t = threadIdx.x;
    int i = blockIdx.x * SCAN_BLK + t;
    int v = (i < M2) ? data[i] : 0;
    lds[t] = v;
    __syncthreads();
    for (int off = 1; off < SCAN_BLK; off <<= 1) {
        int tmp = (t >= off) ? lds[t - off] : 0;
        __syncthreads();
        lds[t] += tmp;
        __syncthreads();
    }
    if (i < M2) data[i] = lds[t] - v;
    if (t == SCAN_BLK - 1) blocksum[blockIdx.x] = lds[t];
}

// local exclusive scan of blocksum into sboff[MAXNBS] (call with >= MAXNBS threads)
__device__ __forceinline__ void local_boff_scan(const int* __restrict__ blocksum,
                                                int* __restrict__ sboff, int nbs, int t) {
    int own = 0;
    if (t < MAXNBS) { own = (t < nbs) ? blocksum[t] : 0; sboff[t] = own; }
    __syncthreads();
    for (int off = 1; off < MAXNBS; off <<= 1) {
        int v = (t < MAXNBS && t >= off) ? sboff[t - off] : 0;
        __syncthreads();
        if (t < MAXNBS) sboff[t] += v;
        __syncthreads();
    }
    if (t < MAXNBS) sboff[t] -= own;   // exclusive
    __syncthreads();
}

// Pass 2: FUSED scatter: packed edges by dst-bucket + src shorts by src-bucket.
__global__ void fused_scatter_kernel(const int* __restrict__ src, const int* __restrict__ dst,
                                     const int* __restrict__ counts, const int* __restrict__ blocksum,
                                     unsigned* __restrict__ packed, unsigned short* __restrict__ psrc,
                                     int E, int B, int nb, int M, int nbs) {
    extern __shared__ int smem[];            // loff[2B] | sboff[MAXNBS]
    int* loff  = smem;
    int* sboff = smem + 2 * B;
    int t = threadIdx.x, b = blockIdx.x;
    local_boff_scan(blocksum, sboff, nbs, t);
    for (int i = t; i < B; i += blockDim.x) {
        int id  = i * nb + b;
        int id2 = M + i * nb + b;
        loff[i]     = counts[id]  + sboff[id >> 10];
        loff[B + i] = counts[id2] + sboff[id2 >> 10] - E;   // src half starts at E
    }
    __syncthreads();
    int base = b * CHUNK;
    int end  = base + CHUNK < E ? base + CHUNK : E;
    int i4beg = base >> 2, i4end = end >> 2;
    for (int i = i4beg + t; i < i4end; i += blockDim.x) {
        int4 s4 = ((const int4*)src)[i];
        int4 d4 = ((const int4*)dst)[i];
        #pragma unroll
        for (int k = 0; k < 4; ++k) {
            int s = (k == 0) ? s4.x : (k == 1) ? s4.y : (k == 2) ? s4.z : s4.w;
            int d = (k == 0) ? d4.x : (k == 1) ? d4.y : (k == 2) ? d4.z : d4.w;
            int pos = atomicAdd(&loff[d >> LB], 1);
            packed[pos] = (unsigned)s | ((unsigned)(d & (BN - 1)) << 17);
            int pos2 = atomicAdd(&loff[B + (s >> LB)], 1);
            psrc[pos2] = (unsigned short)(s & (BN - 1));
        }
    }
    if (b == (int)gridDim.x - 1 && t == 0) {               // scalar tail
        for (int e = i4end << 2; e < end; ++e) {
            int s = src[e], d = dst[e];
            int pos = atomicAdd(&loff[d >> LB], 1);
            packed[pos] = (unsigned)s | ((unsigned)(d & (BN - 1)) << 17);
            int pos2 = atomicAdd(&loff[B + (s >> LB)], 1);
            psrc[pos2] = (unsigned short)(s & (BN - 1));
        }
    }
}

// Fused: (A) src-bucket count -> dz{d0,invdeg}, rA; (B) dst counting sort ->
// PADDED csr (rows x4, 16B-aligned bases, dummy node N in pads/gaps), row_ptr.
__global__ void bucket_kernel(const unsigned short* __restrict__ psrc,
                              const unsigned* __restrict__ packed,
                              const int* __restrict__ counts, const int* __restrict__ blocksum,
                              const float* __restrict__ d0,
                              float2* __restrict__ dz, float* __restrict__ rA, float* __restrict__ rB,
                              int* __restrict__ csr_src, int* __restrict__ row_ptr,
                              int N, int E, int B, int nb, int M, int nbs) {
    __shared__ int cnt[8 * BN];
    __shared__ int off[BN];
    __shared__ int sboff[MAXNBS];
    __shared__ int sh_padtot;
    int t = threadIdx.x, b = blockIdx.x, w = t >> 6;
    int g = (b << LB) + t;
    local_boff_scan(blocksum, sboff, nbs, t);
    // ---- phase A: src fine count -> dz, r0
    for (int i = t; i < 8 * BN; i += blockDim.x) cnt[i] = 0;
    __syncthreads();
    int id = M + b * nb;
    int beg = counts[id] + sboff[id >> 10] - E;
    int end;
    if (b + 1 < B) { int id2 = M + (b + 1) * nb; end = counts[id2] + sboff[id2 >> 10] - E; }
    else end = E;
    for (int e = beg + t; e < end; e += blockDim.x)
        atomicAdd(&cnt[(w << 9) + psrc[e]], 1);
    __syncthreads();
    if (g < N) {
        int tot = 0;
        #pragma unroll
        for (int r = 0; r < 8; ++r) tot += cnt[(r << 9) + t];
        float v = 1.0f / ((float)tot + 1e-9f);
        dz[g] = make_float2(d0[g], v);
        rA[g] = v;                 // r_0 = 1 * invdeg
    }
    if (b == 0 && t == 0) { rA[N] = 0.0f; rB[N] = 0.0f; }   // dummy node
    __syncthreads();
    // ---- phase B: dst counting sort with row padding
    for (int i = t; i < 8 * BN; i += blockDim.x) cnt[i] = 0;
    __syncthreads();
    id = b * nb;
    beg = counts[id] + sboff[id >> 10];
    if (b + 1 < B) { int id2 = (b + 1) * nb; end = counts[id2] + sboff[id2 >> 10]; }
    else end = E;
    for (int e = beg + t; e < end; e += blockDim.x)
        atomicAdd(&cnt[(w << 9) + (packed[e] >> 17)], 1);
    __syncthreads();
    int tot = 0;
    #pragma unroll
    for (int r = 0; r < 8; ++r) tot += cnt[(r << 9) + t];
    int ptot = (tot + 3) & ~3;                     // padded row length
    off[t] = ptot;
    __syncthreads();
    for (int s = 1; s < BN; s <<= 1) {             // Hillis-Steele inclusive
        int v = (t >= s) ? off[t - s] : 0;
        __syncthreads();
        off[t] += v;
        __syncthreads();
    }
    if (t == BN - 1) sh_padtot = off[t];
    const int csrBase = ((beg + 3) & ~3) + BSLACK * b;   // 16B-aligned
    int rowStart = csrBase + off[t] - ptot;
    if (g < N) row_ptr[g] = rowStart;
    if (g == N - 1) row_ptr[N] = rowStart + ptot;        // global csr end
    {
        int base2 = rowStart;                      // per-wave pre-reserved cursors
        #pragma unroll
        for (int r = 0; r < 8; ++r) { int c = cnt[(r << 9) + t]; cnt[(r << 9) + t] = base2; base2 += c; }
    }
    __syncthreads();
    for (int e = beg + t; e < end; e += blockDim.x) {
        unsigned v = packed[e];
        int pos = atomicAdd(&cnt[(w << 9) + (v >> 17)], 1);
        csr_src[pos] = (int)(v & 0x1FFFFu);
    }
    // row pads -> dummy N
    for (int k = rowStart + tot; k < rowStart + ptot; ++k) csr_src[k] = N;
    __syncthreads();
    // inter-bucket gap -> dummy N (last bucket needs none: row_ptr[N] is exact)
    if (b + 1 < B) {
        int nextBase = ((end + 3) & ~3) + BSLACK * (b + 1);
        for (int k = csrBase + sh_padtot + t; k < nextBase; k += blockDim.x)
            csr_src[k] = N;
    }
}

// ---------- flow loop: quad-lane per node, one int4 csr load per lane ----------
template <bool LAST>
__global__ void spmv_q_kernel(const int* __restrict__ row_ptr, const int* __restrict__ csr_src,
                              const float* __restrict__ r_in, const float2* __restrict__ dz,
                              float* __restrict__ r_out, float2* __restrict__ rz_out, int N) {
    int tid = blockIdx.x * blockDim.x + threadIdx.x;
    int n = tid >> 2;
    if (n >= N) return;
    int q = tid & 3;
    int beg = row_ptr[n], end = row_ptr[n + 1];
    float a0 = 0.0f, a1 = 0.0f;
    for (int j = beg + (q << 2); j < end; j += 16) {
        int4 c = *(const int4*)(csr_src + j);    // 16B-aligned (rows padded x4)
        a0 += r_in[c.x] + r_in[c.z];
        a1 += r_in[c.y] + r_in[c.w];
    }
    float a = a0 + a1;
    a += __shfl_xor(a, 1, 64);
    a += __shfl_xor(a, 2, 64);
    if (q == 0) {
        float2 dzn = dz[n];                      // one 8B load: {d0, invdeg}
        float p = a - dzn.x;
        p = p > 0.0f ? p : 0.0f;
        if (LAST) rz_out[n] = make_float2(p * dzn.y, dzn.y);
        else      r_out[n] = p * dzn.y;
    }
}

// flow[e]=rz.x, fw[e]=rz.y from ONE 8B gather; per-block partial of flow^2.
__global__ void final_kernel(const int* __restrict__ src, const float2* __restrict__ rz,
                             float* __restrict__ flow, float* __restrict__ fw,
                             float* __restrict__ partials, int E) {
    int i = blockIdx.x * blockDim.x + threadIdx.x;
    int E4 = E >> 2;
    float f2 = 0.0f;
    if (i < E4) {
        int4 s4 = ((const int4*)src)[i];
        float2 a = rz[s4.x], b = rz[s4.y], c = rz[s4.z], d = rz[s4.w];
        int e = i << 2;
        flow[e] = a.x; flow[e + 1] = b.x; flow[e + 2] = c.x; flow[e + 3] = d.x;
        fw[e]   = a.y; fw[e + 1]   = b.y; fw[e + 2]   = c.y; fw[e + 3]   = d.y;
        f2 = a.x * a.x + b.x * b.x + c.x * c.x + d.x * d.x;
    }
    if (blockIdx.x == 0 && threadIdx.x == 0) {   // tail (E % 4)
        for (int e = E4 << 2; e < E; ++e) {
            float2 a = rz[src[e]];
            flow[e] = a.x; fw[e] = a.y;
            f2 += a.x * a.x;
        }
    }
    #pragma unroll
    for (int off = 32; off > 0; off >>= 1) f2 += __shfl_down(f2, off, 64);
    __shared__ float wsum[BLK / 64];
    int lane = threadIdx.x & 63, w = threadIdx.x >> 6;
    if (lane == 0) wsum[w] = f2;
    __syncthreads();
    if (threadIdx.x == 0) {
        float s = 0.0f;
        #pragma unroll
        for (int k = 0; k < BLK / 64; ++k) s += wsum[k];
        partials[blockIdx.x] = s;
    }
}

__global__ void reduce_cost_kernel(const float* __restrict__ partials, float* __restrict__ cost, int n) {
    float s = 0.0f;
    for (int i = threadIdx.x; i < n; i += blockDim.x) s += partials[i];
    #pragma unroll
    for (int off = 32; off > 0; off >>= 1) s += __shfl_down(s, off, 64);
    __shared__ float wsum[16];
    int lane = threadIdx.x & 63, w = threadIdx.x >> 6;
    if (lane == 0) wsum[w] = s;
    __syncthreads();
    if (threadIdx.x == 0) {
        float t = 0.0f;
        for (int k = 0; k < (int)(blockDim.x / 64); ++k) t += wsum[k];
        cost[0] = t;
    }
}

extern "C" void kernel_launch(void* const* d_in, const int* in_sizes, int n_in,
                              void* d_out, int out_size, void* d_ws, size_t ws_size,
                              hipStream_t stream) {
    const float* demands  = (const float*)d_in[0];
    const int*   edge_src = (const int*)d_in[2];
    const int*   edge_dst = (const int*)d_in[3];
    const int N = in_sizes[0];
    const int E = in_sizes[2];

    float* out  = (float*)d_out;
    float* cost = out;
    float* flow = out + 1;
    float* fw   = out + 1 + E;

    const int B   = (N + BN - 1) >> LB;              // 196 buckets
    const int nb  = (E + CHUNK - 1) / CHUNK;         // 196 partition blocks
    const int M   = B * nb;
    const int M2  = 2 * M;                           // ~77K
    const int nbs = (M2 + SCAN_BLK - 1) / SCAN_BLK;  // 76 (< MAXNBS)
    const int gridF = ((E >> 2) + BLK - 1) / BLK;    // final (vec4)
    const int gridS = (4 * N + BLK - 1) / BLK;       // spmv (quad-lane/node)
    const int csrCap = ((E + 3) & ~3) + BSLACK * B + 16;  // padded csr extent

    auto align16 = [](size_t x) { return (x + 15) & ~size_t(15); };
    char* ws = (char*)d_ws;
    size_t o = 0;
    float2*   dz       = (float2*)(ws + o);   o += align16((size_t)N * 8);
    float*    rA       = (float*)(ws + o);    o += align16((size_t)(N + 1) * 4);  // +dummy
    float*    rB       = (float*)(ws + o);    o += align16((size_t)(N + 1) * 4);  // +dummy
    float2*   rz2      = (float2*)(ws + o);   o += align16((size_t)N * 8);
    int*      row_ptr  = (int*)(ws + o);      o += align16((size_t)(N + 1) * 4);
    int*      counts   = (int*)(ws + o);      o += align16((size_t)M2 * 4);
    int*      blocksum = (int*)(ws + o);      o += align16((size_t)nbs * 4);
    unsigned* packed   = (unsigned*)(ws + o); o += align16((size_t)E * 4);
    unsigned short* psrc = (unsigned short*)(ws + o); o += align16((size_t)E * 2);
    int*      csr_src  = (int*)(ws + o);      o += align16((size_t)csrCap * 4);
    float*    partials = (float*)(ws + o);    o += align16((size_t)gridF * 4);

    hist_kernel<<<nb, BLK_B, (size_t)(16 * B) * 4, stream>>>(edge_src, edge_dst, counts, E, B, nb, M);
    scan_block_kernel<<<(M2 + SCAN_BLK - 1) / SCAN_BLK, SCAN_BLK, 0, stream>>>(counts, blocksum, M2);
    fused_scatter_kernel<<<nb, BLK_B, (size_t)(2 * B + MAXNBS) * 4, stream>>>(
        edge_src, edge_dst, counts, blocksum, packed, psrc, E, B, nb, M, nbs);
    bucket_kernel<<<B, BN, 0, stream>>>(psrc, packed, counts, blocksum, demands,
                                        dz, rA, rB, csr_src, row_ptr, N, E, B, nb, M, nbs);

    float* r_cur = rA;
    float* r_nxt = rB;
    for (int it = 0; it < 9; ++it) {
        spmv_q_kernel<false><<<gridS, BLK, 0, stream>>>(row_ptr, csr_src, r_cur, dz,
                                                        r_nxt, nullptr, N);
        float* t = r_cur; r_cur = r_nxt; r_nxt = t;
    }
    spmv_q_kernel<true><<<gridS, BLK, 0, stream>>>(row_ptr, csr_src, r_cur, dz,
                                                   nullptr, rz2, N);

    final_kernel<<<gridF, BLK, 0, stream>>>(edge_src, rz2, flow, fw, partials, E);
    reduce_cost_kernel<<<1, 1024, 0, stream>>>(partials, cost, gridF);
}

// Round 12
// 162.548 us; speedup vs baseline: 1.7432x; 1.7432x over previous
//
#include <hip/hip_runtime.h>

// SparseMCFModel: the GNN is dead code. fw_e = 1/(outdeg(src_e)+1e-9) exactly
// (softmax over per-segment-constant scores). Flow loop collapses to node
// space: r_0 = invdeg; r_{k+1}[n] = relu(sum_{e:dst=n} r_k[src_e] - d0[n]) *
// invdeg[n]; flow[e] = r_10[src[e]]; fw[e] = invdeg[src[e]]; cost = sum flow^2.
//
// R1->R2: no single-address cost atomic; CSR gather spmv.       1268 -> 428 us
// R2->R3: bucket partition (atomic-free except outdeg hist).     428 -> 284 us
// R3->R4: zero global atomics, CHUNK 4096.                       284 -> 219 us
// R4->R5: full counting sort -> CSR-by-dst, atomic-free spmv.    219 -> 220 us
// R5->R6: smaller counts matrix, fused scatter, fused bucket.    220 -> 188 us
// R6->R7: cooperative grid.sync — ~100us/sync (XCD non-coherence). -> 1188 us
// R7->R8: threadfence-ticket = same-address atomic serialization.  -> 230 us
// R8->R9: ticket dropped; last spmv iter emits float2{r10,invdeg}.  -> 172 us
// R9->R10: CHUNK 8192, no scan_partials kernel, dz float2.          -> 170 us
// R10->R11: int4-padded CSR, BUT end=row_ptr[n+1] made each bucket's last
//   node scan the ~1.5K-entry slack gap -> 1 straggler wave per 2 blocks,
//   dependent-chain latency x10 iters = +113us.                    -> 283 us
// R11->R12: row spans int2{beg,len} instead of a shared row_ptr fence: the
//   gap belongs to NO row, never scanned, never even initialized. Keeps the
//   aligned int4 CSR reads + dummy-node row pads (<=3/row). Max row = max
//   in-degree (~50) -> no stragglers.

static constexpr int BLK      = 256;    // spmv / final / reduce
static constexpr int BLK_B    = 512;    // hist / scatter / bucket
static constexpr int SCAN_BLK = 1024;
static constexpr int CHUNK    = 8192;   // edges per partition block
static constexpr int LB       = 9;      // log2(nodes per bucket)
static constexpr int BN       = 512;    // nodes per bucket
static constexpr int MAXNBS   = 256;    // max scan blocks (nbs = 76 here)
static constexpr int BSLACK   = 1540;   // per-bucket csr slack (>= 3*512 + align)

// ---------- build passes ----------

__global__ void hist_kernel(const int* __restrict__ src, const int* __restrict__ dst,
                            int* __restrict__ counts, int E, int B, int nb, int M) {
    extern __shared__ int lh[];              // 8 replicas x [0,B) dst | [B,2B) src
    const int nbins = 2 * B;
    for (int i = threadIdx.x; i < 8 * nbins; i += blockDim.x) lh[i] = 0;
    __syncthreads();
    int* my = lh + (threadIdx.x >> 6) * nbins;
    int base = blockIdx.x * CHUNK;
    int end  = base + CHUNK < E ? base + CHUNK : E;
    int i4beg = base >> 2, i4end = end >> 2;
    for (int i = i4beg + threadIdx.x; i < i4end; i += blockDim.x) {
        int4 s4 = ((const int4*)src)[i];
        int4 d4 = ((const int4*)dst)[i];
        atomicAdd(&my[d4.x >> LB], 1); atomicAdd(&my[B + (s4.x >> LB)], 1);
        atomicAdd(&my[d4.y >> LB], 1); atomicAdd(&my[B + (s4.y >> LB)], 1);
        atomicAdd(&my[d4.z >> LB], 1); atomicAdd(&my[B + (s4.z >> LB)], 1);
        atomicAdd(&my[d4.w >> LB], 1); atomicAdd(&my[B + (s4.w >> LB)], 1);
    }
    if (blockIdx.x == (int)gridDim.x - 1 && threadIdx.x == 0) {   // scalar tail
        for (int e = i4end << 2; e < end; ++e) {
            atomicAdd(&my[dst[e] >> LB], 1);
            atomicAdd(&my[B + (src[e] >> LB)], 1);
        }
    }
    __syncthreads();
    for (int i = threadIdx.x; i < nbins; i += blockDim.x) {
        int s = 0;
        #pragma unroll
        for (int r = 0; r < 8; ++r) s += lh[r * nbins + i];
        if (i < B) counts[i * nb + blockIdx.x] = s;               // bin-major
        else       counts[M + (i - B) * nb + blockIdx.x] = s;
    }
}

__global__ void scan_block_kernel(int* __restrict__ data, int* __restrict__ blocksum, int M2) {
    __shared__ int lds[SCAN_BLK];
    int t = threadIdx.x;
    int i = blockIdx.x * SCAN_BLK + t;
    int v = (i < M2) ? data[i] : 0;
    lds[t] = v;
    __syncthreads();
    for (int off = 1; off < SCAN_BLK; off <<= 1) {
        int tmp = (t >= off) ? lds[t - off] : 0;
        __syncthreads();
        lds[t] += tmp;
        __syncthreads();
    }
    if (i < M2) data[i] = lds[t] - v;
    if (t == SCAN_BLK - 1) blocksum[blockIdx.x] = lds[t];
}

// local exclusive scan of blocksum into sboff[MAXNBS] (call with >= MAXNBS threads)
__device__ __forceinline__ void local_boff_scan(const int* __restrict__ blocksum,
                                                int* __restrict__ sboff, int nbs, int t) {
    int own = 0;
    if (t < MAXNBS) { own = (t < nbs) ? blocksum[t] : 0; sboff[t] = own; }
    __syncthreads();
    for (int off = 1; off < MAXNBS; off <<= 1) {
        int v = (t < MAXNBS && t >= off) ? sboff[t - off] : 0;
        __syncthreads();
        if (t < MAXNBS) sboff[t] += v;
        __syncthreads();
    }
    if (t < MAXNBS) sboff[t] -= own;   // exclusive
    __syncthreads();
}

// Pass 2: FUSED scatter: packed edges by dst-bucket + src shorts by src-bucket.
__global__ void fused_scatter_kernel(const int* __restrict__ src, const int* __restrict__ dst,
                                     const int* __restrict__ counts, const int* __restrict__ blocksum,
                                     unsigned* __restrict__ packed, unsigned short* __restrict__ psrc,
                                     int E, int B, int nb, int M, int nbs) {
    extern __shared__ int smem[];            // loff[2B] | sboff[MAXNBS]
    int* loff  = smem;
    int* sboff = smem + 2 * B;
    int t = threadIdx.x, b = blockIdx.x;
    local_boff_scan(blocksum, sboff, nbs, t);
    for (int i = t; i < B; i += blockDim.x) {
        int id  = i * nb + b;
        int id2 = M + i * nb + b;
        loff[i]     = counts[id]  + sboff[id >> 10];
        loff[B + i] = counts[id2] + sboff[id2 >> 10] - E;   // src half starts at E
    }
    __syncthreads();
    int base = b * CHUNK;
    int end  = base + CHUNK < E ? base + CHUNK : E;
    int i4beg = base >> 2, i4end = end >> 2;
    for (int i = i4beg + t; i < i4end; i += blockDim.x) {
        int4 s4 = ((const int4*)src)[i];
        int4 d4 = ((const int4*)dst)[i];
        #pragma unroll
        for (int k = 0; k < 4; ++k) {
            int s = (k == 0) ? s4.x : (k == 1) ? s4.y : (k == 2) ? s4.z : s4.w;
            int d = (k == 0) ? d4.x : (k == 1) ? d4.y : (k == 2) ? d4.z : d4.w;
            int pos = atomicAdd(&loff[d >> LB], 1);
            packed[pos] = (unsigned)s | ((unsigned)(d & (BN - 1)) << 17);
            int pos2 = atomicAdd(&loff[B + (s >> LB)], 1);
            psrc[pos2] = (unsigned short)(s & (BN - 1));
        }
    }
    if (b == (int)gridDim.x - 1 && t == 0) {               // scalar tail
        for (int e = i4end << 2; e < end; ++e) {
            int s = src[e], d = dst[e];
            int pos = atomicAdd(&loff[d >> LB], 1);
            packed[pos] = (unsigned)s | ((unsigned)(d & (BN - 1)) << 17);
            int pos2 = atomicAdd(&loff[B + (s >> LB)], 1);
            psrc[pos2] = (unsigned short)(s & (BN - 1));
        }
    }
}

// Fused: (A) src-bucket count -> dz{d0,invdeg}, rA; (B) dst counting sort ->
// PADDED csr (rows x4, aligned; dummy node N in row pads; gaps UNREAD),
// row spans int2{beg,len}.
__global__ void bucket_kernel(const unsigned short* __restrict__ psrc,
                              const unsigned* __restrict__ packed,
                              const int* __restrict__ counts, const int* __restrict__ blocksum,
                              const float* __restrict__ d0,
                              float2* __restrict__ dz, float* __restrict__ rA, float* __restrict__ rB,
                              int* __restrict__ csr_src, int2* __restrict__ row_span,
                              int N, int E, int B, int nb, int M, int nbs) {
    __shared__ int cnt[8 * BN];
    __shared__ int off[BN];
    __shared__ int sboff[MAXNBS];
    int t = threadIdx.x, b = blockIdx.x, w = t >> 6;
    int g = (b << LB) + t;
    local_boff_scan(blocksum, sboff, nbs, t);
    // ---- phase A: src fine count -> dz, r0
    for (int i = t; i < 8 * BN; i += blockDim.x) cnt[i] = 0;
    __syncthreads();
    int id = M + b * nb;
    int beg = counts[id] + sboff[id >> 10] - E;
    int end;
    if (b + 1 < B) { int id2 = M + (b + 1) * nb; end = counts[id2] + sboff[id2 >> 10] - E; }
    else end = E;
    for (int e = beg + t; e < end; e += blockDim.x)
        atomicAdd(&cnt[(w << 9) + psrc[e]], 1);
    __syncthreads();
    if (g < N) {
        int tot = 0;
        #pragma unroll
        for (int r = 0; r < 8; ++r) tot += cnt[(r << 9) + t];
        float v = 1.0f / ((float)tot + 1e-9f);
        dz[g] = make_float2(d0[g], v);
        rA[g] = v;                 // r_0 = 1 * invdeg
    }
    if (b == 0 && t == 0) { rA[N] = 0.0f; rB[N] = 0.0f; }   // dummy node
    __syncthreads();
    // ---- phase B: dst counting sort with row padding
    for (int i = t; i < 8 * BN; i += blockDim.x) cnt[i] = 0;
    __syncthreads();
    id = b * nb;
    beg = counts[id] + sboff[id >> 10];
    if (b + 1 < B) { int id2 = (b + 1) * nb; end = counts[id2] + sboff[id2 >> 10]; }
    else end = E;
    for (int e = beg + t; e < end; e += blockDim.x)
        atomicAdd(&cnt[(w << 9) + (packed[e] >> 17)], 1);
    __syncthreads();
    int tot = 0;
    #pragma unroll
    for (int r = 0; r < 8; ++r) tot += cnt[(r << 9) + t];
    int ptot = (tot + 3) & ~3;                     // padded row length
    off[t] = ptot;
    __syncthreads();
    for (int s = 1; s < BN; s <<= 1) {             // Hillis-Steele inclusive
        int v = (t >= s) ? off[t - s] : 0;
        __syncthreads();
        off[t] += v;
        __syncthreads();
    }
    const int csrBase = ((beg + 3) & ~3) + BSLACK * b;   // 16B-aligned
    int rowStart = csrBase + off[t] - ptot;
    if (g < N) row_span[g] = make_int2(rowStart, ptot);  // gap belongs to NO row
    {
        int base2 = rowStart;                      // per-wave pre-reserved cursors
        #pragma unroll
        for (int r = 0; r < 8; ++r) { int c = cnt[(r << 9) + t]; cnt[(r << 9) + t] = base2; base2 += c; }
    }
    __syncthreads();
    for (int e = beg + t; e < end; e += blockDim.x) {
        unsigned v = packed[e];
        int pos = atomicAdd(&cnt[(w << 9) + (v >> 17)], 1);
        csr_src[pos] = (int)(v & 0x1FFFFu);
    }
    // row pads -> dummy N (gaps between buckets are never read: no fill)
    for (int k = rowStart + tot; k < rowStart + ptot; ++k) csr_src[k] = N;
}

// ---------- flow loop: quad-lane per node, one int4 csr load per lane ----------
template <bool LAST>
__global__ void spmv_q_kernel(const int2* __restrict__ row_span, const int* __restrict__ csr_src,
                              const float* __restrict__ r_in, const float2* __restrict__ dz,
                              float* __restrict__ r_out, float2* __restrict__ rz_out, int N) {
    int tid = blockIdx.x * blockDim.x + threadIdx.x;
    int n = tid >> 2;
    if (n >= N) return;
    int q = tid & 3;
    int2 rp = row_span[n];                       // {beg, padded len}
    int end = rp.x + rp.y;
    float a0 = 0.0f, a1 = 0.0f;
    for (int j = rp.x + (q << 2); j < end; j += 16) {
        int4 c = *(const int4*)(csr_src + j);    // 16B-aligned (rows padded x4)
        a0 += r_in[c.x] + r_in[c.z];
        a1 += r_in[c.y] + r_in[c.w];
    }
    float a = a0 + a1;
    a += __shfl_xor(a, 1, 64);
    a += __shfl_xor(a, 2, 64);
    if (q == 0) {
        float2 dzn = dz[n];                      // one 8B load: {d0, invdeg}
        float p = a - dzn.x;
        p = p > 0.0f ? p : 0.0f;
        if (LAST) rz_out[n] = make_float2(p * dzn.y, dzn.y);
        else      r_out[n] = p * dzn.y;
    }
}

// flow[e]=rz.x, fw[e]=rz.y from ONE 8B gather; per-block partial of flow^2.
__global__ void final_kernel(const int* __restrict__ src, const float2* __restrict__ rz,
                             float* __restrict__ flow, float* __restrict__ fw,
                             float* __restrict__ partials, int E) {
    int i = blockIdx.x * blockDim.x + threadIdx.x;
    int E4 = E >> 2;
    float f2 = 0.0f;
    if (i < E4) {
        int4 s4 = ((const int4*)src)[i];
        float2 a = rz[s4.x], b = rz[s4.y], c = rz[s4.z], d = rz[s4.w];
        int e = i << 2;
        flow[e] = a.x; flow[e + 1] = b.x; flow[e + 2] = c.x; flow[e + 3] = d.x;
        fw[e]   = a.y; fw[e + 1]   = b.y; fw[e + 2]   = c.y; fw[e + 3]   = d.y;
        f2 = a.x * a.x + b.x * b.x + c.x * c.x + d.x * d.x;
    }
    if (blockIdx.x == 0 && threadIdx.x == 0) {   // tail (E % 4)
        for (int e = E4 << 2; e < E; ++e) {
            float2 a = rz[src[e]];
            flow[e] = a.x; fw[e] = a.y;
            f2 += a.x * a.x;
        }
    }
    #pragma unroll
    for (int off = 32; off > 0; off >>= 1) f2 += __shfl_down(f2, off, 64);
    __shared__ float wsum[BLK / 64];
    int lane = threadIdx.x & 63, w = threadIdx.x >> 6;
    if (lane == 0) wsum[w] = f2;
    __syncthreads();
    if (threadIdx.x == 0) {
        float s = 0.0f;
        #pragma unroll
        for (int k = 0; k < BLK / 64; ++k) s += wsum[k];
        partials[blockIdx.x] = s;
    }
}

__global__ void reduce_cost_kernel(const float* __restrict__ partials, float* __restrict__ cost, int n) {
    float s = 0.0f;
    for (int i = threadIdx.x; i < n; i += blockDim.x) s += partials[i];
    #pragma unroll
    for (int off = 32; off > 0; off >>= 1) s += __shfl_down(s, off, 64);
    __shared__ float wsum[16];
    int lane = threadIdx.x & 63, w = threadIdx.x >> 6;
    if (lane == 0) wsum[w] = s;
    __syncthreads();
    if (threadIdx.x == 0) {
        float t = 0.0f;
        for (int k = 0; k < (int)(blockDim.x / 64); ++k) t += wsum[k];
        cost[0] = t;
    }
}

extern "C" void kernel_launch(void* const* d_in, const int* in_sizes, int n_in,
                              void* d_out, int out_size, void* d_ws, size_t ws_size,
                              hipStream_t stream) {
    const float* demands  = (const float*)d_in[0];
    const int*   edge_src = (const int*)d_in[2];
    const int*   edge_dst = (const int*)d_in[3];
    const int N = in_sizes[0];
    const int E = in_sizes[2];

    float* out  = (float*)d_out;
    float* cost = out;
    float* flow = out + 1;
    float* fw   = out + 1 + E;

    const int B   = (N + BN - 1) >> LB;              // 196 buckets
    const int nb  = (E + CHUNK - 1) / CHUNK;         // 196 partition blocks
    const int M   = B * nb;
    const int M2  = 2 * M;                           // ~77K
    const int nbs = (M2 + SCAN_BLK - 1) / SCAN_BLK;  // 76 (< MAXNBS)
    const int gridF = ((E >> 2) + BLK - 1) / BLK;    // final (vec4)
    const int gridS = (4 * N + BLK - 1) / BLK;       // spmv (quad-lane/node)
    const int csrCap = ((E + 3) & ~3) + BSLACK * B + 16;  // padded csr extent

    auto align16 = [](size_t x) { return (x + 15) & ~size_t(15); };
    char* ws = (char*)d_ws;
    size_t o = 0;
    float2*   dz       = (float2*)(ws + o);   o += align16((size_t)N * 8);
    float*    rA       = (float*)(ws + o);    o += align16((size_t)(N + 1) * 4);  // +dummy
    float*    rB       = (float*)(ws + o);    o += align16((size_t)(N + 1) * 4);  // +dummy
    float2*   rz2      = (float2*)(ws + o);   o += align16((size_t)N * 8);
    int2*     row_span = (int2*)(ws + o);     o += align16((size_t)N * 8);
    int*      counts   = (int*)(ws + o);      o += align16((size_t)M2 * 4);
    int*      blocksum = (int*)(ws + o);      o += align16((size_t)nbs * 4);
    unsigned* packed   = (unsigned*)(ws + o); o += align16((size_t)E * 4);
    unsigned short* psrc = (unsigned short*)(ws + o); o += align16((size_t)E * 2);
    int*      csr_src  = (int*)(ws + o);      o += align16((size_t)csrCap * 4);
    float*    partials = (float*)(ws + o);    o += align16((size_t)gridF * 4);

    hist_kernel<<<nb, BLK_B, (size_t)(16 * B) * 4, stream>>>(edge_src, edge_dst, counts, E, B, nb, M);
    scan_block_kernel<<<(M2 + SCAN_BLK - 1) / SCAN_BLK, SCAN_BLK, 0, stream>>>(counts, blocksum, M2);
    fused_scatter_kernel<<<nb, BLK_B, (size_t)(2 * B + MAXNBS) * 4, stream>>>(
        edge_src, edge_dst, counts, blocksum, packed, psrc, E, B, nb, M, nbs);
    bucket_kernel<<<B, BN, 0, stream>>>(psrc, packed, counts, blocksum, demands,
                                        dz, rA, rB, csr_src, row_span, N, E, B, nb, M, nbs);

    float* r_cur = rA;
    float* r_nxt = rB;
    for (int it = 0; it < 9; ++it) {
        spmv_q_kernel<false><<<gridS, BLK, 0, stream>>>(row_span, csr_src, r_cur, dz,
                                                        r_nxt, nullptr, N);
        float* t = r_cur; r_cur = r_nxt; r_nxt = t;
    }
    spmv_q_kernel<true><<<gridS, BLK, 0, stream>>>(row_span, csr_src, r_cur, dz,
                                                   nullptr, rz2, N);

    final_kernel<<<gridF, BLK, 0, stream>>>(edge_src, rz2, flow, fw, partials, E);
    reduce_cost_kernel<<<1, 1024, 0, stream>>>(partials, cost, gridF);
}

// Round 13
// 159.164 us; speedup vs baseline: 1.7803x; 1.0213x over previous
//
#include <hip/hip_runtime.h>

// SparseMCFModel: the GNN is dead code. fw_e = 1/(outdeg(src_e)+1e-9) exactly
// (softmax over per-segment-constant scores). Flow loop collapses to node
// space: r_0 = invdeg; r_{k+1}[n] = relu(sum_{e:dst=n} r_k[src_e] - d0[n]) *
// invdeg[n]; flow[e] = r_10[src[e]]; fw[e] = invdeg[src[e]]; cost = sum flow^2.
//
// R1->R2: no single-address cost atomic; CSR gather spmv.       1268 -> 428 us
// R2->R3: bucket partition (atomic-free except outdeg hist).     428 -> 284 us
// R3->R4: zero global atomics, CHUNK 4096.                       284 -> 219 us
// R4->R5: full counting sort -> CSR-by-dst, atomic-free spmv.    219 -> 220 us
// R5->R6: smaller counts matrix, fused scatter, fused bucket.    220 -> 188 us
// R6->R7: cooperative grid.sync — ~100us/sync (XCD non-coherence). -> 1188 us
// R7->R8: threadfence-ticket = same-address atomic serialization.  -> 230 us
// R8->R9: ticket dropped; last spmv iter emits float2{r10,invdeg}.  -> 172 us
// R9->R10: CHUNK 8192, no scan_partials kernel, dz float2.          -> 170 us
// R10->R11: int4 CSR but bucket-last rows scanned the slack gap.    -> 283 us
// R11->R12: row spans int2{beg,len}: gap belongs to NO row.         -> 162 us
// R12->R13: latency-hiding only. Octo-lane spmv (8 lanes/node, 800K threads:
//   deg<=32 in ONE int4+4 gathers, loop almost never iterates; 2x TLP on the
//   L2-gather-bound inner loop). Vec8 final (8 rz gathers in flight/thread).

static constexpr int BLK      = 256;    // spmv / final / reduce
static constexpr int BLK_B    = 512;    // hist / scatter / bucket
static constexpr int SCAN_BLK = 1024;
static constexpr int CHUNK    = 8192;   // edges per partition block
static constexpr int LB       = 9;      // log2(nodes per bucket)
static constexpr int BN       = 512;    // nodes per bucket
static constexpr int MAXNBS   = 256;    // max scan blocks (nbs = 76 here)
static constexpr int BSLACK   = 1540;   // per-bucket csr slack (>= 3*512 + align)

// ---------- build passes ----------

__global__ void hist_kernel(const int* __restrict__ src, const int* __restrict__ dst,
                            int* __restrict__ counts, int E, int B, int nb, int M) {
    extern __shared__ int lh[];              // 8 replicas x [0,B) dst | [B,2B) src
    const int nbins = 2 * B;
    for (int i = threadIdx.x; i < 8 * nbins; i += blockDim.x) lh[i] = 0;
    __syncthreads();
    int* my = lh + (threadIdx.x >> 6) * nbins;
    int base = blockIdx.x * CHUNK;
    int end  = base + CHUNK < E ? base + CHUNK : E;
    int i4beg = base >> 2, i4end = end >> 2;
    for (int i = i4beg + threadIdx.x; i < i4end; i += blockDim.x) {
        int4 s4 = ((const int4*)src)[i];
        int4 d4 = ((const int4*)dst)[i];
        atomicAdd(&my[d4.x >> LB], 1); atomicAdd(&my[B + (s4.x >> LB)], 1);
        atomicAdd(&my[d4.y >> LB], 1); atomicAdd(&my[B + (s4.y >> LB)], 1);
        atomicAdd(&my[d4.z >> LB], 1); atomicAdd(&my[B + (s4.z >> LB)], 1);
        atomicAdd(&my[d4.w >> LB], 1); atomicAdd(&my[B + (s4.w >> LB)], 1);
    }
    if (blockIdx.x == (int)gridDim.x - 1 && threadIdx.x == 0) {   // scalar tail
        for (int e = i4end << 2; e < end; ++e) {
            atomicAdd(&my[dst[e] >> LB], 1);
            atomicAdd(&my[B + (src[e] >> LB)], 1);
        }
    }
    __syncthreads();
    for (int i = threadIdx.x; i < nbins; i += blockDim.x) {
        int s = 0;
        #pragma unroll
        for (int r = 0; r < 8; ++r) s += lh[r * nbins + i];
        if (i < B) counts[i * nb + blockIdx.x] = s;               // bin-major
        else       counts[M + (i - B) * nb + blockIdx.x] = s;
    }
}

__global__ void scan_block_kernel(int* __restrict__ data, int* __restrict__ blocksum, int M2) {
    __shared__ int lds[SCAN_BLK];
    int t = threadIdx.x;
    int i = blockIdx.x * SCAN_BLK + t;
    int v = (i < M2) ? data[i] : 0;
    lds[t] = v;
    __syncthreads();
    for (int off = 1; off < SCAN_BLK; off <<= 1) {
        int tmp = (t >= off) ? lds[t - off] : 0;
        __syncthreads();
        lds[t] += tmp;
        __syncthreads();
    }
    if (i < M2) data[i] = lds[t] - v;
    if (t == SCAN_BLK - 1) blocksum[blockIdx.x] = lds[t];
}

// local exclusive scan of blocksum into sboff[MAXNBS] (call with >= MAXNBS threads)
__device__ __forceinline__ void local_boff_scan(const int* __restrict__ blocksum,
                                                int* __restrict__ sboff, int nbs, int t) {
    int own = 0;
    if (t < MAXNBS) { own = (t < nbs) ? blocksum[t] : 0; sboff[t] = own; }
    __syncthreads();
    for (int off = 1; off < MAXNBS; off <<= 1) {
        int v = (t < MAXNBS && t >= off) ? sboff[t - off] : 0;
        __syncthreads();
        if (t < MAXNBS) sboff[t] += v;
        __syncthreads();
    }
    if (t < MAXNBS) sboff[t] -= own;   // exclusive
    __syncthreads();
}

// Pass 2: FUSED scatter: packed edges by dst-bucket + src shorts by src-bucket.
__global__ void fused_scatter_kernel(const int* __restrict__ src, const int* __restrict__ dst,
                                     const int* __restrict__ counts, const int* __restrict__ blocksum,
                                     unsigned* __restrict__ packed, unsigned short* __restrict__ psrc,
                                     int E, int B, int nb, int M, int nbs) {
    extern __shared__ int smem[];            // loff[2B] | sboff[MAXNBS]
    int* loff  = smem;
    int* sboff = smem + 2 * B;
    int t = threadIdx.x, b = blockIdx.x;
    local_boff_scan(blocksum, sboff, nbs, t);
    for (int i = t; i < B; i += blockDim.x) {
        int id  = i * nb + b;
        int id2 = M + i * nb + b;
        loff[i]     = counts[id]  + sboff[id >> 10];
        loff[B + i] = counts[id2] + sboff[id2 >> 10] - E;   // src half starts at E
    }
    __syncthreads();
    int base = b * CHUNK;
    int end  = base + CHUNK < E ? base + CHUNK : E;
    int i4beg = base >> 2, i4end = end >> 2;
    for (int i = i4beg + t; i < i4end; i += blockDim.x) {
        int4 s4 = ((const int4*)src)[i];
        int4 d4 = ((const int4*)dst)[i];
        #pragma unroll
        for (int k = 0; k < 4; ++k) {
            int s = (k == 0) ? s4.x : (k == 1) ? s4.y : (k == 2) ? s4.z : s4.w;
            int d = (k == 0) ? d4.x : (k == 1) ? d4.y : (k == 2) ? d4.z : d4.w;
            int pos = atomicAdd(&loff[d >> LB], 1);
            packed[pos] = (unsigned)s | ((unsigned)(d & (BN - 1)) << 17);
            int pos2 = atomicAdd(&loff[B + (s >> LB)], 1);
            psrc[pos2] = (unsigned short)(s & (BN - 1));
        }
    }
    if (b == (int)gridDim.x - 1 && t == 0) {               // scalar tail
        for (int e = i4end << 2; e < end; ++e) {
            int s = src[e], d = dst[e];
            int pos = atomicAdd(&loff[d >> LB], 1);
            packed[pos] = (unsigned)s | ((unsigned)(d & (BN - 1)) << 17);
            int pos2 = atomicAdd(&loff[B + (s >> LB)], 1);
            psrc[pos2] = (unsigned short)(s & (BN - 1));
        }
    }
}

// Fused: (A) src-bucket count -> dz{d0,invdeg}, rA; (B) dst counting sort ->
// PADDED csr (rows x4, aligned; dummy node N in row pads; gaps UNREAD),
// row spans int2{beg,len}.
__global__ void bucket_kernel(const unsigned short* __restrict__ psrc,
                              const unsigned* __restrict__ packed,
                              const int* __restrict__ counts, const int* __restrict__ blocksum,
                              const float* __restrict__ d0,
                              float2* __restrict__ dz, float* __restrict__ rA, float* __restrict__ rB,
                              int* __restrict__ csr_src, int2* __restrict__ row_span,
                              int N, int E, int B, int nb, int M, int nbs) {
    __shared__ int cnt[8 * BN];
    __shared__ int off[BN];
    __shared__ int sboff[MAXNBS];
    int t = threadIdx.x, b = blockIdx.x, w = t >> 6;
    int g = (b << LB) + t;
    local_boff_scan(blocksum, sboff, nbs, t);
    // ---- phase A: src fine count -> dz, r0
    for (int i = t; i < 8 * BN; i += blockDim.x) cnt[i] = 0;
    __syncthreads();
    int id = M + b * nb;
    int beg = counts[id] + sboff[id >> 10] - E;
    int end;
    if (b + 1 < B) { int id2 = M + (b + 1) * nb; end = counts[id2] + sboff[id2 >> 10] - E; }
    else end = E;
    for (int e = beg + t; e < end; e += blockDim.x)
        atomicAdd(&cnt[(w << 9) + psrc[e]], 1);
    __syncthreads();
    if (g < N) {
        int tot = 0;
        #pragma unroll
        for (int r = 0; r < 8; ++r) tot += cnt[(r << 9) + t];
        float v = 1.0f / ((float)tot + 1e-9f);
        dz[g] = make_float2(d0[g], v);
        rA[g] = v;                 // r_0 = 1 * invdeg
    }
    if (b == 0 && t == 0) { rA[N] = 0.0f; rB[N] = 0.0f; }   // dummy node
    __syncthreads();
    // ---- phase B: dst counting sort with row padding
    for (int i = t; i < 8 * BN; i += blockDim.x) cnt[i] = 0;
    __syncthreads();
    id = b * nb;
    beg = counts[id] + sboff[id >> 10];
    if (b + 1 < B) { int id2 = (b + 1) * nb; end = counts[id2] + sboff[id2 >> 10]; }
    else end = E;
    for (int e = beg + t; e < end; e += blockDim.x)
        atomicAdd(&cnt[(w << 9) + (packed[e] >> 17)], 1);
    __syncthreads();
    int tot = 0;
    #pragma unroll
    for (int r = 0; r < 8; ++r) tot += cnt[(r << 9) + t];
    int ptot = (tot + 3) & ~3;                     // padded row length
    off[t] = ptot;
    __syncthreads();
    for (int s = 1; s < BN; s <<= 1) {             // Hillis-Steele inclusive
        int v = (t >= s) ? off[t - s] : 0;
        __syncthreads();
        off[t] += v;
        __syncthreads();
    }
    const int csrBase = ((beg + 3) & ~3) + BSLACK * b;   // 16B-aligned
    int rowStart = csrBase + off[t] - ptot;
    if (g < N) row_span[g] = make_int2(rowStart, ptot);  // gap belongs to NO row
    {
        int base2 = rowStart;                      // per-wave pre-reserved cursors
        #pragma unroll
        for (int r = 0; r < 8; ++r) { int c = cnt[(r << 9) + t]; cnt[(r << 9) + t] = base2; base2 += c; }
    }
    __syncthreads();
    for (int e = beg + t; e < end; e += blockDim.x) {
        unsigned v = packed[e];
        int pos = atomicAdd(&cnt[(w << 9) + (v >> 17)], 1);
        csr_src[pos] = (int)(v & 0x1FFFFu);
    }
    // row pads -> dummy N (gaps between buckets are never read: no fill)
    for (int k = rowStart + tot; k < rowStart + ptot; ++k) csr_src[k] = N;
}

// ---------- flow loop: OCTO-lane per node (deg<=32 in one int4/lane) ----------
template <bool LAST>
__global__ void spmv_o_kernel(const int2* __restrict__ row_span, const int* __restrict__ csr_src,
                              const float* __restrict__ r_in, const float2* __restrict__ dz,
                              float* __restrict__ r_out, float2* __restrict__ rz_out, int N) {
    int tid = blockIdx.x * blockDim.x + threadIdx.x;
    int n = tid >> 3;
    if (n >= N) return;
    int q = tid & 7;
    int2 rp = row_span[n];                       // {beg, padded len}
    int end = rp.x + rp.y;
    float a0 = 0.0f, a1 = 0.0f;
    for (int j = rp.x + (q << 2); j < end; j += 32) {
        int4 c = *(const int4*)(csr_src + j);    // 16B-aligned (rows padded x4)
        a0 += r_in[c.x] + r_in[c.z];
        a1 += r_in[c.y] + r_in[c.w];
    }
    float a = a0 + a1;
    a += __shfl_xor(a, 1, 64);
    a += __shfl_xor(a, 2, 64);
    a += __shfl_xor(a, 4, 64);
    if (q == 0) {
        float2 dzn = dz[n];                      // one 8B load: {d0, invdeg}
        float p = a - dzn.x;
        p = p > 0.0f ? p : 0.0f;
        if (LAST) rz_out[n] = make_float2(p * dzn.y, dzn.y);
        else      r_out[n] = p * dzn.y;
    }
}

// flow[e]=rz.x, fw[e]=rz.y from ONE 8B gather; vec8 per thread; per-block
// partial of flow^2.
__global__ void final_kernel(const int* __restrict__ src, const float2* __restrict__ rz,
                             float* __restrict__ flow, float* __restrict__ fw,
                             float* __restrict__ partials, int E) {
    int i = blockIdx.x * blockDim.x + threadIdx.x;
    int E8 = E >> 3;
    float f2 = 0.0f;
    if (i < E8) {
        int4 sa = ((const int4*)src)[2 * i];
        int4 sb = ((const int4*)src)[2 * i + 1];
        float2 a = rz[sa.x], b = rz[sa.y], c = rz[sa.z], d = rz[sa.w];
        float2 e2 = rz[sb.x], f = rz[sb.y], g = rz[sb.z], h = rz[sb.w];
        int e = i << 3;
        flow[e]     = a.x;  flow[e + 1] = b.x;  flow[e + 2] = c.x;  flow[e + 3] = d.x;
        flow[e + 4] = e2.x; flow[e + 5] = f.x;  flow[e + 6] = g.x;  flow[e + 7] = h.x;
        fw[e]     = a.y;  fw[e + 1] = b.y;  fw[e + 2] = c.y;  fw[e + 3] = d.y;
        fw[e + 4] = e2.y; fw[e + 5] = f.y;  fw[e + 6] = g.y;  fw[e + 7] = h.y;
        f2 = a.x * a.x + b.x * b.x + c.x * c.x + d.x * d.x
           + e2.x * e2.x + f.x * f.x + g.x * g.x + h.x * h.x;
    }
    if (blockIdx.x == 0 && threadIdx.x == 0) {   // tail (E % 8)
        for (int e = E8 << 3; e < E; ++e) {
            float2 a = rz[src[e]];
            flow[e] = a.x; fw[e] = a.y;
            f2 += a.x * a.x;
        }
    }
    #pragma unroll
    for (int off = 32; off > 0; off >>= 1) f2 += __shfl_down(f2, off, 64);
    __shared__ float wsum[BLK / 64];
    int lane = threadIdx.x & 63, w = threadIdx.x >> 6;
    if (lane == 0) wsum[w] = f2;
    __syncthreads();
    if (threadIdx.x == 0) {
        float s = 0.0f;
        #pragma unroll
        for (int k = 0; k < BLK / 64; ++k) s += wsum[k];
        partials[blockIdx.x] = s;
    }
}

__global__ void reduce_cost_kernel(const float* __restrict__ partials, float* __restrict__ cost, int n) {
    float s = 0.0f;
    for (int i = threadIdx.x; i < n; i += blockDim.x) s += partials[i];
    #pragma unroll
    for (int off = 32; off > 0; off >>= 1) s += __shfl_down(s, off, 64);
    __shared__ float wsum[16];
    int lane = threadIdx.x & 63, w = threadIdx.x >> 6;
    if (lane == 0) wsum[w] = s;
    __syncthreads();
    if (threadIdx.x == 0) {
        float t = 0.0f;
        for (int k = 0; k < (int)(blockDim.x / 64); ++k) t += wsum[k];
        cost[0] = t;
    }
}

extern "C" void kernel_launch(void* const* d_in, const int* in_sizes, int n_in,
                              void* d_out, int out_size, void* d_ws, size_t ws_size,
                              hipStream_t stream) {
    const float* demands  = (const float*)d_in[0];
    const int*   edge_src = (const int*)d_in[2];
    const int*   edge_dst = (const int*)d_in[3];
    const int N = in_sizes[0];
    const int E = in_sizes[2];

    float* out  = (float*)d_out;
    float* cost = out;
    float* flow = out + 1;
    float* fw   = out + 1 + E;

    const int B   = (N + BN - 1) >> LB;              // 196 buckets
    const int nb  = (E + CHUNK - 1) / CHUNK;         // 196 partition blocks
    const int M   = B * nb;
    const int M2  = 2 * M;                           // ~77K
    const int nbs = (M2 + SCAN_BLK - 1) / SCAN_BLK;  // 76 (< MAXNBS)
    const int gridF = ((E >> 3) + BLK - 1) / BLK;    // final (vec8)
    const int gridS = (8 * N + BLK - 1) / BLK;       // spmv (octo-lane/node)
    const int csrCap = ((E + 3) & ~3) + BSLACK * B + 16;  // padded csr extent

    auto align16 = [](size_t x) { return (x + 15) & ~size_t(15); };
    char* ws = (char*)d_ws;
    size_t o = 0;
    float2*   dz       = (float2*)(ws + o);   o += align16((size_t)N * 8);
    float*    rA       = (float*)(ws + o);    o += align16((size_t)(N + 1) * 4);  // +dummy
    float*    rB       = (float*)(ws + o);    o += align16((size_t)(N + 1) * 4);  // +dummy
    float2*   rz2      = (float2*)(ws + o);   o += align16((size_t)N * 8);
    int2*     row_span = (int2*)(ws + o);     o += align16((size_t)N * 8);
    int*      counts   = (int*)(ws + o);      o += align16((size_t)M2 * 4);
    int*      blocksum = (int*)(ws + o);      o += align16((size_t)nbs * 4);
    unsigned* packed   = (unsigned*)(ws + o); o += align16((size_t)E * 4);
    unsigned short* psrc = (unsigned short*)(ws + o); o += align16((size_t)E * 2);
    int*      csr_src  = (int*)(ws + o);      o += align16((size_t)csrCap * 4);
    float*    partials = (float*)(ws + o);    o += align16((size_t)gridF * 4);

    hist_kernel<<<nb, BLK_B, (size_t)(16 * B) * 4, stream>>>(edge_src, edge_dst, counts, E, B, nb, M);
    scan_block_kernel<<<(M2 + SCAN_BLK - 1) / SCAN_BLK, SCAN_BLK, 0, stream>>>(counts, blocksum, M2);
    fused_scatter_kernel<<<nb, BLK_B, (size_t)(2 * B + MAXNBS) * 4, stream>>>(
        edge_src, edge_dst, counts, blocksum, packed, psrc, E, B, nb, M, nbs);
    bucket_kernel<<<B, BN, 0, stream>>>(psrc, packed, counts, blocksum, demands,
                                        dz, rA, rB, csr_src, row_span, N, E, B, nb, M, nbs);

    float* r_cur = rA;
    float* r_nxt = rB;
    for (int it = 0; it < 9; ++it) {
        spmv_o_kernel<false><<<gridS, BLK, 0, stream>>>(row_span, csr_src, r_cur, dz,
                                                        r_nxt, nullptr, N);
        float* t = r_cur; r_cur = r_nxt; r_nxt = t;
    }
    spmv_o_kernel<true><<<gridS, BLK, 0, stream>>>(row_span, csr_src, r_cur, dz,
                                                   nullptr, rz2, N);

    final_kernel<<<gridF, BLK, 0, stream>>>(edge_src, rz2, flow, fw, partials, E);
    reduce_cost_kernel<<<1, 1024, 0, stream>>>(partials, cost, gridF);
}